// Round 10
// baseline (32.911 us; speedup 1.0000x reference)
//
#include <hip/hip_runtime.h>

#define HIDDEN   1024
#define NEXP     8
#define NTOK     32768           // 4 * 8192
#define TOK_PER_WAVE 8
#define WAVES_PER_BLOCK 4
#define NBLOCKS  (NTOK / (TOK_PER_WAVE * WAVES_PER_BLOCK))   // 1024

// Dual-token 64-lane reduction, stage-interleaved (ILP 2 on DS pipe).
// Per-token op sequence bitwise identical to proven rounds 1-9.
__device__ __forceinline__ void split_reduce8x2(const float (&A)[8], const float (&B)[8],
                                                int lane, float& rA, float& rB) {
    float a4A[4], a4B[4];
    {
        const bool hi = (lane & 4) != 0;
        #pragma unroll
        for (int j = 0; j < 4; ++j) {
            float sA = hi ? A[j] : A[j + 4];
            float sB = hi ? B[j] : B[j + 4];
            float vA = __shfl_xor(sA, 4, 64);
            float vB = __shfl_xor(sB, 4, 64);
            a4A[j] = (hi ? A[j + 4] : A[j]) + vA;
            a4B[j] = (hi ? B[j + 4] : B[j]) + vB;
        }
    }
    float a2A[2], a2B[2];
    {
        const bool hi = (lane & 2) != 0;
        #pragma unroll
        for (int j = 0; j < 2; ++j) {
            float sA = hi ? a4A[j] : a4A[j + 2];
            float sB = hi ? a4B[j] : a4B[j + 2];
            float vA = __shfl_xor(sA, 2, 64);
            float vB = __shfl_xor(sB, 2, 64);
            a2A[j] = (hi ? a4A[j + 2] : a4A[j]) + vA;
            a2B[j] = (hi ? a4B[j + 2] : a4B[j]) + vB;
        }
    }
    float a1A, a1B;
    {
        const bool hi = (lane & 1) != 0;
        float sA = hi ? a2A[0] : a2A[1];
        float sB = hi ? a2B[0] : a2B[1];
        float vA = __shfl_xor(sA, 1, 64);
        float vB = __shfl_xor(sB, 1, 64);
        a1A = (hi ? a2A[1] : a2A[0]) + vA;
        a1B = (hi ? a2B[1] : a2B[0]) + vB;
    }
    {
        float vA = __shfl_xor(a1A, 8, 64);
        float vB = __shfl_xor(a1B, 8, 64);
        a1A += vA; a1B += vB;
        vA = __shfl_xor(a1A, 16, 64);
        vB = __shfl_xor(a1B, 16, 64);
        a1A += vA; a1B += vB;
        vA = __shfl_xor(a1A, 32, 64);
        vB = __shfl_xor(a1B, 32, 64);
        a1A += vA; a1B += vB;
    }
    rA = a1A; rB = a1B;
}

// Per-lane-group softmax+top2 (unchanged, proven rounds 2-9).
__device__ __forceinline__ void softmax_top2_lane(float selv, int lane,
                                                  float& w1, float& w2,
                                                  int& i1, int& i2, float& myp) {
    const int gbase = lane & 56;
    float l[8];
    #pragma unroll
    for (int e = 0; e < 8; ++e) l[e] = __shfl(selv, gbase + e, 64);
    float m = l[0];
    #pragma unroll
    for (int e = 1; e < 8; ++e) m = fmaxf(m, l[e]);
    float p[8];
    float s = 0.f;
    #pragma unroll
    for (int e = 0; e < 8; ++e) { p[e] = __expf(l[e] - m); s += p[e]; }
    const float inv = 1.f / s;

    i1 = 0; float v1 = p[0];
    #pragma unroll
    for (int e = 1; e < 8; ++e) { if (p[e] > v1) { v1 = p[e]; i1 = e; } }
    i2 = -1; float v2 = -1.f;
    #pragma unroll
    for (int e = 0; e < 8; ++e) { if (e != i1 && p[e] > v2) { v2 = p[e]; i2 = e; } }

    const float wsum = v1 + v2;
    w1 = v1 / wsum;
    w2 = v2 / wsum;
    myp = p[lane & 7] * inv;
}

__device__ __forceinline__ void load_pair(const float4* __restrict__ h4,
                                          size_t tok, int lane,
                                          float4 (&h0)[4], float4 (&h1)[4]) {
    const size_t base = tok * 256;   // 256 float4 per row
    #pragma unroll
    for (int j = 0; j < 4; ++j) h0[j] = h4[base + j * 64 + lane];
    #pragma unroll
    for (int j = 0; j < 4; ++j) h1[j] = h4[base + 256 + j * 64 + lane];
}

// W read from LDS (s_w), 4 x ds_read_b128 per expert per pair.
// Same element mapping as rounds 2-9 -> bit-identical FMAs.
__device__ __forceinline__ void process_pair(const float4 (&h0)[4], const float4 (&h1)[4],
                                             const float4* __restrict__ s_w,
                                             int lane, int t0,
                                             float* __restrict__ out_w,
                                             float* __restrict__ out_sel,
                                             float& ps_acc, unsigned* s_cnt) {
    float acc0[8], acc1[8];
    #pragma unroll
    for (int e = 0; e < 8; ++e) {
        float4 Wf[4];
        #pragma unroll
        for (int j = 0; j < 4; ++j) Wf[j] = s_w[e * 256 + j * 64 + lane];
        float a = 0.f, c = 0.f;
        #pragma unroll
        for (int j = 0; j < 4; ++j) {
            a = fmaf(h0[j].x, Wf[j].x, a);
            a = fmaf(h0[j].y, Wf[j].y, a);
            a = fmaf(h0[j].z, Wf[j].z, a);
            a = fmaf(h0[j].w, Wf[j].w, a);
            c = fmaf(h1[j].x, Wf[j].x, c);
            c = fmaf(h1[j].y, Wf[j].y, c);
            c = fmaf(h1[j].z, Wf[j].z, c);
            c = fmaf(h1[j].w, Wf[j].w, c);
        }
        acc0[e] = a; acc1[e] = c;
    }

    float r0, r1;
    split_reduce8x2(acc0, acc1, lane, r0, r1);

    const int tokSel = (lane >> 3) & 1;      // 8-lane groups alternate tokens
    const float selv = tokSel ? r1 : r0;

    float w1, w2, myp; int i1, i2;
    softmax_top2_lane(selv, lane, w1, w2, i1, i2, myp);

    // lanes 0-15 own aux prob accumulation (expert lane&7, token lane>>3)
    ps_acc += myp;

    // expert-count: lanes 0,1 (token0 i1,i2) and 8,9 (token1 i1,i2)
    if ((lane & 54) == 0)
        atomicAdd(&s_cnt[(lane & 1) ? i2 : i1], 1u);

    // writes: lane 0 -> token t0, lane 8 -> token t0+1
    if ((lane & 55) == 0) {
        const int t = t0 + tokSel;
        ((float2*)out_w)[t]   = make_float2(w1, w2);
        ((float2*)out_sel)[t] = make_float2((float)i1, (float)i2);
    }
}

// launch_bounds: max-threads only (round 3: min-waves=4 forced 64-VGPR
// target -> 122 MB spill, 3.5x regression). Depth-2 pipeline: 3 named
// pair-buffers, explicit unroll (static indexing only — runtime-indexed
// vector arrays go to scratch). Pairs p2/p3 get ~2 process_pairs of load
// cover vs depth-1's ~1, closing the residual vmcnt stall.
__global__ __launch_bounds__(256)
void moe_router_kernel(const float* __restrict__ h, const float* __restrict__ wg,
                       float* __restrict__ out_w, float* __restrict__ out_sel,
                       float* __restrict__ ws) {
    __shared__ float4   s_w[2048];     // 32 KB: full W_gate [8][1024] f32
    __shared__ float    s_ps[8];
    __shared__ unsigned s_cnt[8];
    const int tid  = threadIdx.x;
    const int lane = tid & 63;
    const int widx = tid >> 6;

    if (tid < 8) { s_ps[tid] = 0.f; s_cnt[tid] = 0u; }
    {
        const float4* wg4 = (const float4*)wg;
        #pragma unroll
        for (int i = 0; i < 8; ++i)
            s_w[tid + i * 256] = wg4[tid + i * 256];
    }
    __syncthreads();

    const int gw      = blockIdx.x * WAVES_PER_BLOCK + widx;
    const int tokBase = gw * TOK_PER_WAVE;
    const float4* h4  = (const float4*)h;
    float ps_acc = 0.f;

    float4 hA0[4], hA1[4], hB0[4], hB1[4], hC0[4], hC1[4];

    // 4 pairs per wave: p0=tokBase, p1=+2, p2=+4, p3=+6
    load_pair(h4, (size_t)(tokBase),     lane, hA0, hA1);   // p0
    load_pair(h4, (size_t)(tokBase + 2), lane, hB0, hB1);   // p1
    load_pair(h4, (size_t)(tokBase + 4), lane, hC0, hC1);   // p2

    process_pair(hA0, hA1, s_w, lane, tokBase,     out_w, out_sel, ps_acc, s_cnt);
    load_pair(h4, (size_t)(tokBase + 6), lane, hA0, hA1);   // p3 (reuses A regs)
    process_pair(hB0, hB1, s_w, lane, tokBase + 2, out_w, out_sel, ps_acc, s_cnt);
    process_pair(hC0, hC1, s_w, lane, tokBase + 4, out_w, out_sel, ps_acc, s_cnt);
    process_pair(hA0, hA1, s_w, lane, tokBase + 6, out_w, out_sel, ps_acc, s_cnt);

    if (lane < 16) atomicAdd(&s_ps[lane & 7], ps_acc);
    __syncthreads();

    // ws layout: [16][NBLOCKS] so finalize reads coalesced float4.
    if (tid < 8) {
        ws[(size_t)tid * NBLOCKS + blockIdx.x]       = s_ps[tid];
        ws[(size_t)(tid + 8) * NBLOCKS + blockIdx.x] = (float)s_cnt[tid];  // exact (<=64)
    }
}

__global__ void moe_finalize_kernel(const float* __restrict__ ws,
                                    float* __restrict__ aux_out) {
    __shared__ float s[256];
    const int t = threadIdx.x;
    const int k = t >> 4;         // 0-7: ps_e, 8-15: cnt_e
    const int j = t & 15;         // 16 threads per k
    const float4* w4 = (const float4*)(ws + (size_t)k * NBLOCKS);  // 256 float4 per k
    float acc = 0.f;
    #pragma unroll
    for (int i = 0; i < 16; ++i) {
        float4 v = w4[j + i * 16];
        acc += v.x + v.y + v.z + v.w;
    }
    s[t] = acc;
    __syncthreads();
    if (t < 16) {
        float v = 0.f;
        #pragma unroll
        for (int c = 0; c < 16; ++c) v += s[t * 16 + c];
        s[t] = v;
    }
    __syncthreads();
    if (t == 0) {
        const float invT = 1.0f / (float)NTOK;
        float a = 0.f;
        #pragma unroll
        for (int e = 0; e < 8; ++e)
            a += (s[8 + e] * invT) * (s[e] * invT);
        *aux_out = (float)NEXP * a;
    }
}

extern "C" void kernel_launch(void* const* d_in, const int* in_sizes, int n_in,
                              void* d_out, int out_size, void* d_ws, size_t ws_size,
                              hipStream_t stream) {
    const float* h  = (const float*)d_in[0];   // [4, 8192, 1024] f32
    const float* wg = (const float*)d_in[1];   // [8, 1024] f32

    float* out_w   = (float*)d_out;            // [4,8192,2,1] -> 65536
    float* out_sel = out_w + 65536;            // [4,8192,2]   -> 65536 (as float)
    float* aux     = out_w + 131072;           // scalar

    float* ws = (float*)d_ws;                  // [16][1024] floats (fully rewritten every call)

    moe_router_kernel<<<NBLOCKS, 256, 0, stream>>>(h, wg, out_w, out_sel, ws);
    moe_finalize_kernel<<<1, 256, 0, stream>>>(ws, aux);
}

// Round 12
// 32.540 us; speedup vs baseline: 1.0114x; 1.0114x over previous
//
#include <hip/hip_runtime.h>

#define HIDDEN   1024
#define NEXP     8
#define NTOK     32768           // 4 * 8192
#define TOK_PER_WAVE 8
#define WAVES_PER_BLOCK 4
#define NBLOCKS  (NTOK / (TOK_PER_WAVE * WAVES_PER_BLOCK))   // 1024

// Quad-token 64-lane reduction, stage-interleaved (ILP 4 on DS pipe).
// Per-token op sequence bitwise identical to the proven split_reduce8
// (rounds 1-10): same shuffles, same adds, same order.
__device__ __forceinline__ void split_reduce8x4(const float (&A)[8], const float (&B)[8],
                                                const float (&C)[8], const float (&D)[8],
                                                int lane,
                                                float& rA, float& rB, float& rC, float& rD) {
    float a4A[4], a4B[4], a4C[4], a4D[4];
    {
        const bool hi = (lane & 4) != 0;
        #pragma unroll
        for (int j = 0; j < 4; ++j) {
            float sA = hi ? A[j] : A[j + 4];
            float sB = hi ? B[j] : B[j + 4];
            float sC = hi ? C[j] : C[j + 4];
            float sD = hi ? D[j] : D[j + 4];
            float vA = __shfl_xor(sA, 4, 64);
            float vB = __shfl_xor(sB, 4, 64);
            float vC = __shfl_xor(sC, 4, 64);
            float vD = __shfl_xor(sD, 4, 64);
            a4A[j] = (hi ? A[j + 4] : A[j]) + vA;
            a4B[j] = (hi ? B[j + 4] : B[j]) + vB;
            a4C[j] = (hi ? C[j + 4] : C[j]) + vC;
            a4D[j] = (hi ? D[j + 4] : D[j]) + vD;
        }
    }
    float a2A[2], a2B[2], a2C[2], a2D[2];
    {
        const bool hi = (lane & 2) != 0;
        #pragma unroll
        for (int j = 0; j < 2; ++j) {
            float sA = hi ? a4A[j] : a4A[j + 2];
            float sB = hi ? a4B[j] : a4B[j + 2];
            float sC = hi ? a4C[j] : a4C[j + 2];
            float sD = hi ? a4D[j] : a4D[j + 2];
            float vA = __shfl_xor(sA, 2, 64);
            float vB = __shfl_xor(sB, 2, 64);
            float vC = __shfl_xor(sC, 2, 64);
            float vD = __shfl_xor(sD, 2, 64);
            a2A[j] = (hi ? a4A[j + 2] : a4A[j]) + vA;
            a2B[j] = (hi ? a4B[j + 2] : a4B[j]) + vB;
            a2C[j] = (hi ? a4C[j + 2] : a4C[j]) + vC;
            a2D[j] = (hi ? a4D[j + 2] : a4D[j]) + vD;
        }
    }
    float a1A, a1B, a1C, a1D;
    {
        const bool hi = (lane & 1) != 0;
        float sA = hi ? a2A[0] : a2A[1];
        float sB = hi ? a2B[0] : a2B[1];
        float sC = hi ? a2C[0] : a2C[1];
        float sD = hi ? a2D[0] : a2D[1];
        float vA = __shfl_xor(sA, 1, 64);
        float vB = __shfl_xor(sB, 1, 64);
        float vC = __shfl_xor(sC, 1, 64);
        float vD = __shfl_xor(sD, 1, 64);
        a1A = (hi ? a2A[1] : a2A[0]) + vA;
        a1B = (hi ? a2B[1] : a2B[0]) + vB;
        a1C = (hi ? a2C[1] : a2C[0]) + vC;
        a1D = (hi ? a2D[1] : a2D[0]) + vD;
    }
    {
        float vA = __shfl_xor(a1A, 8, 64);
        float vB = __shfl_xor(a1B, 8, 64);
        float vC = __shfl_xor(a1C, 8, 64);
        float vD = __shfl_xor(a1D, 8, 64);
        a1A += vA; a1B += vB; a1C += vC; a1D += vD;
        vA = __shfl_xor(a1A, 16, 64);
        vB = __shfl_xor(a1B, 16, 64);
        vC = __shfl_xor(a1C, 16, 64);
        vD = __shfl_xor(a1D, 16, 64);
        a1A += vA; a1B += vB; a1C += vC; a1D += vD;
        vA = __shfl_xor(a1A, 32, 64);
        vB = __shfl_xor(a1B, 32, 64);
        vC = __shfl_xor(a1C, 32, 64);
        vD = __shfl_xor(a1D, 32, 64);
        a1A += vA; a1B += vB; a1C += vC; a1D += vD;
    }
    rA = a1A; rB = a1B; rC = a1C; rD = a1D;
}

// Per-lane-group softmax+top2 (unchanged, proven rounds 2-10). selv = this
// 8-lane-group's token logit for expert (lane&7).
__device__ __forceinline__ void softmax_top2_lane(float selv, int lane,
                                                  float& w1, float& w2,
                                                  int& i1, int& i2, float& myp) {
    const int gbase = lane & 56;
    float l[8];
    #pragma unroll
    for (int e = 0; e < 8; ++e) l[e] = __shfl(selv, gbase + e, 64);
    float m = l[0];
    #pragma unroll
    for (int e = 1; e < 8; ++e) m = fmaxf(m, l[e]);
    float p[8];
    float s = 0.f;
    #pragma unroll
    for (int e = 0; e < 8; ++e) { p[e] = __expf(l[e] - m); s += p[e]; }
    const float inv = 1.f / s;

    i1 = 0; float v1 = p[0];
    #pragma unroll
    for (int e = 1; e < 8; ++e) { if (p[e] > v1) { v1 = p[e]; i1 = e; } }
    i2 = -1; float v2 = -1.f;
    #pragma unroll
    for (int e = 0; e < 8; ++e) { if (e != i1 && p[e] > v2) { v2 = p[e]; i2 = e; } }

    const float wsum = v1 + v2;
    w1 = v1 / wsum;
    w2 = v2 / wsum;
    myp = p[lane & 7] * inv;
}

__device__ __forceinline__ void load_quad(const float4* __restrict__ h4,
                                          size_t tok, int lane,
                                          float4 (&q0)[4], float4 (&q1)[4],
                                          float4 (&q2)[4], float4 (&q3)[4]) {
    const size_t base = tok * 256;   // 256 float4 per row
    #pragma unroll
    for (int j = 0; j < 4; ++j) q0[j] = h4[base +       j * 64 + lane];
    #pragma unroll
    for (int j = 0; j < 4; ++j) q1[j] = h4[base + 256 + j * 64 + lane];
    #pragma unroll
    for (int j = 0; j < 4; ++j) q2[j] = h4[base + 512 + j * 64 + lane];
    #pragma unroll
    for (int j = 0; j < 4; ++j) q3[j] = h4[base + 768 + j * 64 + lane];
}

// 4 tokens per call: W fragments read ONCE from LDS per expert and fed to
// all 4 tokens' FMAs (halves LDS W traffic vs the 2-token version), one
// softmax pass with 4 active lane-groups, 4-way interleaved reduce.
// Per-token arithmetic bit-identical to rounds 1-10.
// ROUND-11 BUG FIX: lane masks. 2-token masks (54/55) excluded lanes
// 16,17,24,25 / 16,24 -> tokens 2,3 of each quad never written (absmax
// 0.934). Quad masks must leave bits 3 AND 4 free:
//   count lanes {0,1,8,9,16,17,24,25}: (lane & 38) == 0   [bits 5,2,1]
//   write lanes {0,8,16,24}:           (lane & 39) == 0   [bits 5,2,1,0]
__device__ __forceinline__ void process_quad(const float4 (&h0)[4], const float4 (&h1)[4],
                                             const float4 (&h2)[4], const float4 (&h3)[4],
                                             const float4* __restrict__ s_w,
                                             int lane, int t0,
                                             float* __restrict__ out_w,
                                             float* __restrict__ out_sel,
                                             float& ps_acc, unsigned* s_cnt) {
    float a0[8], a1[8], a2[8], a3[8];
    #pragma unroll
    for (int e = 0; e < 8; ++e) {
        float4 Wf[4];
        #pragma unroll
        for (int j = 0; j < 4; ++j) Wf[j] = s_w[e * 256 + j * 64 + lane];
        float x0 = 0.f, x1 = 0.f, x2 = 0.f, x3 = 0.f;
        #pragma unroll
        for (int j = 0; j < 4; ++j) {
            x0 = fmaf(h0[j].x, Wf[j].x, x0);
            x0 = fmaf(h0[j].y, Wf[j].y, x0);
            x0 = fmaf(h0[j].z, Wf[j].z, x0);
            x0 = fmaf(h0[j].w, Wf[j].w, x0);
            x1 = fmaf(h1[j].x, Wf[j].x, x1);
            x1 = fmaf(h1[j].y, Wf[j].y, x1);
            x1 = fmaf(h1[j].z, Wf[j].z, x1);
            x1 = fmaf(h1[j].w, Wf[j].w, x1);
            x2 = fmaf(h2[j].x, Wf[j].x, x2);
            x2 = fmaf(h2[j].y, Wf[j].y, x2);
            x2 = fmaf(h2[j].z, Wf[j].z, x2);
            x2 = fmaf(h2[j].w, Wf[j].w, x2);
            x3 = fmaf(h3[j].x, Wf[j].x, x3);
            x3 = fmaf(h3[j].y, Wf[j].y, x3);
            x3 = fmaf(h3[j].z, Wf[j].z, x3);
            x3 = fmaf(h3[j].w, Wf[j].w, x3);
        }
        a0[e] = x0; a1[e] = x1; a2[e] = x2; a3[e] = x3;
    }

    float r0, r1, r2, r3;
    split_reduce8x4(a0, a1, a2, a3, lane, r0, r1, r2, r3);

    const int g = (lane >> 3) & 3;           // lane-group -> token (groups 4-7 duplicate)
    const float selv = (g == 0) ? r0 : (g == 1) ? r1 : (g == 2) ? r2 : r3;

    float w1, w2, myp; int i1, i2;
    softmax_top2_lane(selv, lane, w1, w2, i1, i2, myp);

    // aux prob accumulation: lanes 0-31 own (expert lane&7, token lane>>3)
    ps_acc += myp;                            // flushed for lanes 0-31 only

    // expert-count: lanes 0,1 / 8,9 / 16,17 / 24,25 (tokens 0-3, top1/top2)
    if ((lane & 38) == 0)
        atomicAdd(&s_cnt[(lane & 1) ? i2 : i1], 1u);

    // writes: lanes 0,8,16,24 write tokens t0..t0+3
    if ((lane & 39) == 0) {
        const int t = t0 + g;
        ((float2*)out_w)[t]   = make_float2(w1, w2);
        ((float2*)out_sel)[t] = make_float2((float)i1, (float)i2);
    }
}

// launch_bounds: max-threads only (round 3: min-waves=4 forced 64-VGPR
// target -> 122 MB spill, 3.5x regression). W_gate staged in LDS (round 9,
// +1.7us). Two quads per wave; compiler schedules the B-quad loads under
// the A-quad compute as registers allow.
__global__ __launch_bounds__(256)
void moe_router_kernel(const float* __restrict__ h, const float* __restrict__ wg,
                       float* __restrict__ out_w, float* __restrict__ out_sel,
                       float* __restrict__ ws) {
    __shared__ float4   s_w[2048];     // 32 KB: full W_gate [8][1024] f32
    __shared__ float    s_ps[8];
    __shared__ unsigned s_cnt[8];
    const int tid  = threadIdx.x;
    const int lane = tid & 63;
    const int widx = tid >> 6;

    if (tid < 8) { s_ps[tid] = 0.f; s_cnt[tid] = 0u; }
    {
        const float4* wg4 = (const float4*)wg;
        #pragma unroll
        for (int i = 0; i < 8; ++i)
            s_w[tid + i * 256] = wg4[tid + i * 256];
    }
    __syncthreads();

    const int gw      = blockIdx.x * WAVES_PER_BLOCK + widx;
    const int tokBase = gw * TOK_PER_WAVE;
    const float4* h4  = (const float4*)h;
    float ps_acc = 0.f;

    float4 A0[4], A1[4], A2[4], A3[4];
    float4 B0[4], B1[4], B2[4], B3[4];

    load_quad(h4, (size_t)tokBase,     lane, A0, A1, A2, A3);
    load_quad(h4, (size_t)tokBase + 4, lane, B0, B1, B2, B3);

    process_quad(A0, A1, A2, A3, s_w, lane, tokBase,     out_w, out_sel, ps_acc, s_cnt);
    process_quad(B0, B1, B2, B3, s_w, lane, tokBase + 4, out_w, out_sel, ps_acc, s_cnt);

    if (lane < 32) atomicAdd(&s_ps[lane & 7], ps_acc);
    __syncthreads();

    // ws layout: [16][NBLOCKS] so finalize reads coalesced float4.
    if (tid < 8) {
        ws[(size_t)tid * NBLOCKS + blockIdx.x]       = s_ps[tid];
        ws[(size_t)(tid + 8) * NBLOCKS + blockIdx.x] = (float)s_cnt[tid];  // exact (<=64)
    }
}

__global__ void moe_finalize_kernel(const float* __restrict__ ws,
                                    float* __restrict__ aux_out) {
    __shared__ float s[256];
    const int t = threadIdx.x;
    const int k = t >> 4;         // 0-7: ps_e, 8-15: cnt_e
    const int j = t & 15;         // 16 threads per k
    const float4* w4 = (const float4*)(ws + (size_t)k * NBLOCKS);  // 256 float4 per k
    float acc = 0.f;
    #pragma unroll
    for (int i = 0; i < 16; ++i) {
        float4 v = w4[j + i * 16];
        acc += v.x + v.y + v.z + v.w;
    }
    s[t] = acc;
    __syncthreads();
    if (t < 16) {
        float v = 0.f;
        #pragma unroll
        for (int c = 0; c < 16; ++c) v += s[t * 16 + c];
        s[t] = v;
    }
    __syncthreads();
    if (t == 0) {
        const float invT = 1.0f / (float)NTOK;
        float a = 0.f;
        #pragma unroll
        for (int e = 0; e < 8; ++e)
            a += (s[8 + e] * invT) * (s[e] * invT);
        *aux_out = (float)NEXP * a;
    }
}

extern "C" void kernel_launch(void* const* d_in, const int* in_sizes, int n_in,
                              void* d_out, int out_size, void* d_ws, size_t ws_size,
                              hipStream_t stream) {
    const float* h  = (const float*)d_in[0];   // [4, 8192, 1024] f32
    const float* wg = (const float*)d_in[1];   // [8, 1024] f32

    float* out_w   = (float*)d_out;            // [4,8192,2,1] -> 65536
    float* out_sel = out_w + 65536;            // [4,8192,2]   -> 65536 (as float)
    float* aux     = out_w + 131072;           // scalar

    float* ws = (float*)d_ws;                  // [16][1024] floats (fully rewritten every call)

    moe_router_kernel<<<NBLOCKS, 256, 0, stream>>>(h, wg, out_w, out_sel, ws);
    moe_finalize_kernel<<<1, 256, 0, stream>>>(ws, aux);
}